// Round 1
// baseline (100.593 us; speedup 1.0000x reference)
//
#include <hip/hip_runtime.h>
#include <math.h>

// Problem constants (from reference): x is (B=2048, S=1024, D=12) f32,
// VOTE_PERHEAD = select_num = 24, S = 32*32 so the 2-D conv path is taken.
constexpr int S_  = 1024;
constexpr int D_  = 12;
constexpr int K_  = 24;
constexpr int NT  = 256;   // 4 waves per block

__global__ __launch_bounds__(NT) void mhv_kernel(const float* __restrict__ x,
                                                 float* __restrict__ out_idx,  // B*K
                                                 float* __restrict__ out_cnt)  // B*S
{
    const int b    = blockIdx.x;
    const int tid  = threadIdx.x;
    const int lane = tid & 63;
    const int wid  = tid >> 6;

    __shared__ float sc[S_];     // scores, consumed by phase-1 argmax
    __shared__ int   cnt[S_];    // 0/1 votes; later reused as sort keys
    __shared__ int   conv[S_];   // conv result (integral)
    __shared__ float rvalf[4];
    __shared__ int   rvali[4];
    __shared__ int   ridx[4];

    // ---- load: score[s] = x[b, s+1, 0]; pad s=1023 with -inf ----
    const float* xb = x + (size_t)b * (S_ * D_);
    for (int s = tid; s < S_; s += NT) {
        sc[s]  = (s < S_ - 1) ? xb[(s + 1) * D_] : -INFINITY;
        cnt[s] = 0;
    }
    __syncthreads();

    // ---- phase 1: top-K of score -> cnt[p] = 1 (iterative argmax) ----
    for (int it = 0; it < K_; ++it) {
        float best = -INFINITY;
        int   bi   = S_;
        for (int s = tid; s < S_; s += NT) {
            float v = sc[s];
            if (v > best || (v == best && s < bi)) { best = v; bi = s; }
        }
        #pragma unroll
        for (int off = 32; off > 0; off >>= 1) {
            float ov = __shfl_down(best, off);
            int   oi = __shfl_down(bi, off);
            if (ov > best || (ov == best && oi < bi)) { best = ov; bi = oi; }
        }
        if (lane == 0) { rvalf[wid] = best; ridx[wid] = bi; }
        __syncthreads();
        if (tid == 0) {
            float bv = rvalf[0]; int bx = ridx[0];
            for (int w = 1; w < 4; ++w)
                if (rvalf[w] > bv || (rvalf[w] == bv && ridx[w] < bx)) { bv = rvalf[w]; bx = ridx[w]; }
            sc[bx]  = -INFINITY;  // remove from next argmax
            cnt[bx] = 1;          // vote
        }
        __syncthreads();
    }

    // ---- phase 2: 3x3 conv ([[1,2,1],[2,4,2],[1,2,1]]) on 32x32, zero pad ----
    for (int p = tid; p < S_; p += NT) {
        int r = p >> 5, c = p & 31;
        int acc = 0;
        #pragma unroll
        for (int dr = -1; dr <= 1; ++dr) {
            int rr = r + dr;
            if (rr < 0 || rr >= 32) continue;
            #pragma unroll
            for (int dc = -1; dc <= 1; ++dc) {
                int cc = c + dc;
                if (cc < 0 || cc >= 32) continue;
                int w = ((dr == 0) ? 2 : 1) * ((dc == 0) ? 2 : 1);
                acc += w * cnt[rr * 32 + cc];
            }
        }
        conv[p] = acc;
        out_cnt[(size_t)b * S_ + p] = (float)acc;   // output 1: count
    }
    __syncthreads();

    // ---- phase 3: stable top-K of count (ties -> smaller index first) ----
    // Composite key: count*1024 + (1023 - p). Unique per p; descending key
    // order == stable argsort(-count) order.
    for (int p = tid; p < S_; p += NT) cnt[p] = conv[p] * 1024 + (S_ - 1 - p);
    __syncthreads();

    for (int it = 0; it < K_; ++it) {
        int best = -1, bi = -1;
        for (int p = tid; p < S_; p += NT) {
            int k = cnt[p];
            if (k > best) { best = k; bi = p; }
        }
        #pragma unroll
        for (int off = 32; off > 0; off >>= 1) {
            int ov = __shfl_down(best, off);
            int oi = __shfl_down(bi, off);
            if (ov > best) { best = ov; bi = oi; }
        }
        if (lane == 0) { rvali[wid] = best; ridx[wid] = bi; }
        __syncthreads();
        if (tid == 0) {
            int bv = rvali[0], bx = ridx[0];
            for (int w = 1; w < 4; ++w)
                if (rvali[w] > bv) { bv = rvali[w]; bx = ridx[w]; }
            out_idx[(size_t)b * K_ + it] = (float)(bx + 1);  // output 0: 1-based index
            cnt[bx] = -1;  // remove (all real keys are >= 0)
        }
        __syncthreads();
    }
}

extern "C" void kernel_launch(void* const* d_in, const int* in_sizes, int n_in,
                              void* d_out, int out_size, void* d_ws, size_t ws_size,
                              hipStream_t stream) {
    const float* x = (const float*)d_in[0];
    const int B = in_sizes[0] / (S_ * D_);

    float* out     = (float*)d_out;
    float* out_idx = out;                      // B*K_ elements (patch_idx, 1-based)
    float* out_cnt = out + (size_t)B * K_;     // B*S_ elements (count)

    mhv_kernel<<<dim3(B), dim3(NT), 0, stream>>>(x, out_idx, out_cnt);
}

// Round 2
// 32.922 us; speedup vs baseline: 3.0555x; 3.0555x over previous
//
#include <hip/hip_runtime.h>
#include <math.h>

// x: (B=2048, S=1024, D=12) f32. K = select_num = VOTE_PERHEAD = 24. S = 32*32.
constexpr int S_  = 1024;
constexpr int D_  = 12;
constexpr int K_  = 24;
constexpr int NT  = 256;       // 4 waves
constexpr int EPT = S_ / NT;   // 4 elements per thread

__global__ __launch_bounds__(NT) void mhv_kernel(const float* __restrict__ x,
                                                 float* __restrict__ out_idx,  // B*K
                                                 float* __restrict__ out_cnt)  // B*S
{
    const int b    = blockIdx.x;
    const int tid  = threadIdx.x;
    const int lane = tid & 63;
    const int wid  = tid >> 6;

    __shared__ int          cnt[S_];     // 0/1 votes
    __shared__ unsigned int chist[64];   // coarse histogram (top 6 bits)
    __shared__ unsigned int fhist[256];  // fine histogram (next 8 bits)
    __shared__ int          fsum[257];   // fine suffix sums
    __shared__ unsigned int bc[256];     // phase-1 boundary candidates
    __shared__ int          ck[256];     // phase-3 candidate keys (<= 216)
    __shared__ int          ncand, nc2;
    __shared__ int          sb1, scab1, sT14, sR;

    // ---- init + load scores (registers), monotone bit transform ----
    for (int i = tid; i < S_; i += NT) cnt[i] = 0;
    if (tid < 64) chist[tid] = 0;
    fhist[tid] = 0;
    if (tid == 0) { ncand = 0; nc2 = 0; }

    const float* xb = x + (size_t)b * (S_ * D_);
    unsigned int su[EPT];
    #pragma unroll
    for (int i = 0; i < EPT; ++i) {
        int s = tid + i * NT;
        if (s < S_ - 1) {
            unsigned int bits = __float_as_uint(xb[(s + 1) * D_]);
            // monotone: order(su) == order(float). Finite floats -> su >= 0x00800000 > 0.
            su[i] = (bits & 0x80000000u) ? ~bits : (bits | 0x80000000u);
        } else su[i] = 0u;  // sentinel (position 1023 has no score)
    }
    __syncthreads();

    // ---- coarse histogram ----
    #pragma unroll
    for (int i = 0; i < EPT; ++i)
        if (su[i]) atomicAdd(&chist[su[i] >> 26], 1u);
    __syncthreads();

    // ---- wave 0: suffix-scan 64 coarse bins, pick boundary coarse bin ----
    if (wid == 0) {
        unsigned int h = chist[lane];
        unsigned int val = h;                       // will become sum of bins >= lane
        #pragma unroll
        for (int off = 1; off < 64; off <<= 1) {
            unsigned int t = __shfl_down(val, off);
            if (lane + off < 64) val += t;
        }
        unsigned long long m = __ballot(val >= (unsigned)K_);
        int b1 = 63 - __clzll(m);                   // highest bin with suffix >= K
        unsigned int above = __shfl(val - h, b1);   // count strictly above bin b1 (< K)
        if (lane == 0) { sb1 = b1; scab1 = (int)above; }
    }
    __syncthreads();

    // ---- fine histogram within coarse bin b1 ----
    int b1 = sb1;
    #pragma unroll
    for (int i = 0; i < EPT; ++i)
        if (su[i] && (int)(su[i] >> 26) == b1)
            atomicAdd(&fhist[(su[i] >> 18) & 255u], 1u);
    __syncthreads();

    // ---- wave 0: suffix-scan 256 fine bins (4/lane), pick boundary fine bin ----
    if (wid == 0) {
        unsigned int h0 = fhist[4*lane+0], h1 = fhist[4*lane+1];
        unsigned int h2 = fhist[4*lane+2], h3 = fhist[4*lane+3];
        unsigned int s3 = h3, s2v = h2 + s3, s1v = h1 + s2v, s0v = h0 + s1v;
        unsigned int val = s0v;
        #pragma unroll
        for (int off = 1; off < 64; off <<= 1) {
            unsigned int t = __shfl_down(val, off);
            if (lane + off < 64) val += t;
        }
        unsigned int above = val - s0v;             // sum over lanes > this lane
        fsum[4*lane+0] = (int)(above + s0v);
        fsum[4*lane+1] = (int)(above + s1v);
        fsum[4*lane+2] = (int)(above + s2v);
        fsum[4*lane+3] = (int)(above + s3);
        if (lane == 63) fsum[256] = 0;

        int r1 = K_ - scab1;                        // >= 1 by construction
        int cand = -1;                              // highest of my 4 bins with fsum >= r1
        if      ((int)(above + s3)  >= r1) cand = 4*lane+3;
        else if ((int)(above + s2v) >= r1) cand = 4*lane+2;
        else if ((int)(above + s1v) >= r1) cand = 4*lane+1;
        else if ((int)(above + s0v) >= r1) cand = 4*lane+0;
        unsigned long long m = __ballot(cand >= 0); // nonzero: bin b1 holds >= r1 elems
        int b2 = __shfl(cand, 63 - __clzll(m));
        if (lane == 0) {
            int cab = scab1 + fsum[b2 + 1];         // strictly above 14-bit boundary (< K)
            sT14 = (b1 << 8) | b2;
            sR   = K_ - cab;                        // take R largest from boundary bin
        }
    }
    __syncthreads();

    // ---- mark definite winners; collect boundary candidates ----
    int T14 = sT14;
    #pragma unroll
    for (int i = 0; i < EPT; ++i) {
        if (su[i]) {
            int t = (int)(su[i] >> 18);
            int s = tid + i * NT;
            if (t > T14) {
                cnt[s] = 1;
            } else if (t == T14) {
                int slot = atomicAdd(&ncand, 1);
                // key: remaining 18 value bits desc, then index asc (top_k tie-break)
                if (slot < 256)
                    bc[slot] = ((su[i] & 0x3FFFFu) << 10) | (unsigned)(S_ - 1 - s);
            }
        }
    }
    __syncthreads();

    // ---- exact rank among boundary candidates; top R get a vote ----
    int nc = min(ncand, 256);
    int R  = sR;
    if (tid < nc) {
        unsigned int key = bc[tid];
        int rk = 0;
        for (int j = 0; j < nc; ++j) rk += (bc[j] > key);
        if (rk < R) cnt[S_ - 1 - (int)(key & 1023u)] = 1;
    }
    __syncthreads();

    // ---- 3x3 conv [[1,2,1],[2,4,2],[1,2,1]] on 32x32, write counts,
    //      collect positions with count >= 1 (<= 216 of them) ----
    for (int p = tid; p < S_; p += NT) {
        int r = p >> 5, c = p & 31;
        int acc = 0;
        #pragma unroll
        for (int dr = -1; dr <= 1; ++dr) {
            int rr = r + dr;
            if (rr < 0 || rr >= 32) continue;
            #pragma unroll
            for (int dc = -1; dc <= 1; ++dc) {
                int cc = c + dc;
                if (cc < 0 || cc >= 32) continue;
                int w = ((dr == 0) ? 2 : 1) * ((dc == 0) ? 2 : 1);
                acc += w * cnt[rr * 32 + cc];
            }
        }
        out_cnt[(size_t)b * S_ + p] = (float)acc;
        if (acc > 0) {
            int slot = atomicAdd(&nc2, 1);
            ck[slot] = acc * 1024 + (S_ - 1 - p);   // count desc, index asc
        }
    }
    __syncthreads();

    // ---- exact stable rank of candidates; ranks 0..23 are the output ----
    int n2 = nc2;                                   // 24 <= n2 <= 216
    if (tid < n2) {
        int key = ck[tid];
        int rk = 0;
        for (int j = 0; j < n2; ++j) rk += (ck[j] > key);
        if (rk < K_) out_idx[(size_t)b * K_ + rk] = (float)(S_ - (key & 1023)); // p+1
    }
}

extern "C" void kernel_launch(void* const* d_in, const int* in_sizes, int n_in,
                              void* d_out, int out_size, void* d_ws, size_t ws_size,
                              hipStream_t stream) {
    const float* x = (const float*)d_in[0];
    const int B = in_sizes[0] / (S_ * D_);

    float* out     = (float*)d_out;
    float* out_idx = out;                    // B*K_ (patch_idx, 1-based, as f32)
    float* out_cnt = out + (size_t)B * K_;   // B*S_ (count)

    mhv_kernel<<<dim3(B), dim3(NT), 0, stream>>>(x, out_idx, out_cnt);
}